// Round 9
// baseline (518.736 us; speedup 1.0000x reference)
//
#include <hip/hip_runtime.h>
#include <hip/hip_fp16.h>

#define BSZ 1024   // B
#define VSZ 4096   // V
#define NBLK 32    // sinkhorn blocks (32 j-rows each, 512 threads)
#define JPB 32     // j's per sinkhorn block
#define KPAD 1040  // LDS row stride for K (1024 + 16 floats)

// ---------------- softmax(y/2) row-wise, writes u16 fixed-point probs --------
__global__ __launch_bounds__(256) void softmax_kernel(const float* __restrict__ ys,
                                                      const float* __restrict__ yt,
                                                      unsigned short* __restrict__ ps,
                                                      unsigned short* __restrict__ pt) {
    int row = blockIdx.x;
    const float* src;
    unsigned short* dst;
    if (row < BSZ) { src = ys + (size_t)row * VSZ;         dst = ps + (size_t)row * VSZ; }
    else           { src = yt + (size_t)(row - BSZ) * VSZ; dst = pt + (size_t)(row - BSZ) * VSZ; }
    int t = threadIdx.x;
    float4 v[4];
    float m = -1e30f;
#pragma unroll
    for (int k = 0; k < 4; ++k) {
        v[k] = ((const float4*)src)[t + 256 * k];
        m = fmaxf(m, fmaxf(fmaxf(v[k].x, v[k].y), fmaxf(v[k].z, v[k].w)));
    }
#pragma unroll
    for (int d = 32; d >= 1; d >>= 1) m = fmaxf(m, __shfl_down(m, d));
    __shared__ float sred[4];
    __shared__ float sred2[4];
    int lane = t & 63, wid = t >> 6;
    if (lane == 0) sred[wid] = m;
    __syncthreads();
    m = fmaxf(fmaxf(sred[0], sred[1]), fmaxf(sred[2], sred[3]));
    const float C = 0.7213475204444817f;  // 0.5 * log2(e)  (T = 2)
    float s = 0.f;
#pragma unroll
    for (int k = 0; k < 4; ++k) {
        v[k].x = exp2f((v[k].x - m) * C);
        v[k].y = exp2f((v[k].y - m) * C);
        v[k].z = exp2f((v[k].z - m) * C);
        v[k].w = exp2f((v[k].w - m) * C);
        s += (v[k].x + v[k].y) + (v[k].z + v[k].w);
    }
#pragma unroll
    for (int d = 32; d >= 1; d >>= 1) s += __shfl_down(s, d);
    if (lane == 0) sred2[wid] = s;
    __syncthreads();
    s = (sred2[0] + sred2[1]) + (sred2[2] + sred2[3]);
    float inv = 65535.0f / s;  // fold quantization scale into the normalizer
#pragma unroll
    for (int k = 0; k < 4; ++k) {
        union { unsigned short h[4]; uint2 u; } o;
        o.h[0] = (unsigned short)__float2uint_rn(fminf(v[k].x * inv, 65535.0f));
        o.h[1] = (unsigned short)__float2uint_rn(fminf(v[k].y * inv, 65535.0f));
        o.h[2] = (unsigned short)__float2uint_rn(fminf(v[k].z * inv, 65535.0f));
        o.h[3] = (unsigned short)__float2uint_rn(fminf(v[k].w * inv, 65535.0f));
        ((uint2*)dst)[t + 256 * k] = o.u;
    }
}

// ---------------- W-partial: WT[j][i] = sum_v |ps[i,v] - pt[j,v]| ------------
// R24: 128x128 tile, 256 threads, 8x8 acc/thread. DS reads per SAD halve vs
// the 8x4 (16 b128/vv feed 256 SADs): DS ~33us < VALU floor 55us (v_sad_u16
// is quarter-rate, R22-measured) -> VALU-bound ~60-70us. Register discipline
// that survived R22/R23: q[8] resident (32) + p in PAIRS (8) + acc 64 +
// prefetch 32 + addr ~ 150-190 worst; (256,1) grants up to 256 (R22: 228,
// zero spill). Grid 8x8x4 = 256 blocks = exactly 1/CU; reg-prefetch of kt+1
// issued before the 8192-cyc compute hides HBM. WRITE_SIZE ~16.4e3 KB is the
// no-spill signal.
#define TSI 128  // i-tile
#define TSJ 128  // j-tile
#define LSTR 72  // u16 row stride (144 B): 2-way bank aliasing -> free (m136)

__global__ __launch_bounds__(256, 1) void cdist_kernel(const unsigned short* __restrict__ psh,
                                                       const unsigned short* __restrict__ pth,
                                                       float* __restrict__ spart) {
    __shared__ unsigned short sP[TSI * LSTR];   // 18,432 B
    __shared__ unsigned short sQ[TSJ * LSTR];   // 18,432 B  (36.9 KB)
    const int bi = blockIdx.x;   // 8 i-panels
    const int bj = blockIdx.y;   // 8 j-panels
    const int bv = blockIdx.z;   // 4 v-chunks
    const int t = threadIdx.x;
    const int cl = t & 15;   // i-lane (16)
    const int rl = t >> 4;   // j-lane (16)

    // staging (both arrays): thread t -> row t>>1 (128 rows), half (t&1)*32 u16
    const int sr = t >> 1, sc = (t & 1) * 32;
    const unsigned short* gP = psh + (size_t)(bi * TSI + sr) * VSZ + bv * 1024 + sc;
    const unsigned short* gQ = pth + (size_t)(bj * TSJ + sr) * VSZ + bv * 1024 + sc;
    unsigned short* lP = &sP[sr * LSTR + sc];
    unsigned short* lQ = &sQ[sr * LSTR + sc];

    unsigned acc[8][8];
#pragma unroll
    for (int w = 0; w < 8; ++w)
#pragma unroll
        for (int u = 0; u < 8; ++u) acc[w][u] = 0u;

    {   // stage kt = 0
        uint4 a0 = *(const uint4*)(gP + 0);
        uint4 a1 = *(const uint4*)(gP + 8);
        uint4 a2 = *(const uint4*)(gP + 16);
        uint4 a3 = *(const uint4*)(gP + 24);
        uint4 b0 = *(const uint4*)(gQ + 0);
        uint4 b1 = *(const uint4*)(gQ + 8);
        uint4 b2 = *(const uint4*)(gQ + 16);
        uint4 b3 = *(const uint4*)(gQ + 24);
        *(uint4*)(lP + 0)  = a0;
        *(uint4*)(lP + 8)  = a1;
        *(uint4*)(lP + 16) = a2;
        *(uint4*)(lP + 24) = a3;
        *(uint4*)(lQ + 0)  = b0;
        *(uint4*)(lQ + 8)  = b1;
        *(uint4*)(lQ + 16) = b2;
        *(uint4*)(lQ + 24) = b3;
    }
    __syncthreads();

    for (int kt = 0; kt < 16; ++kt) {
        uint4 ra0, ra1, ra2, ra3, rb0, rb1, rb2, rb3;
        if (kt < 15) {  // prefetch next tile into registers (hides HBM latency)
            const unsigned short* gp = gP + (kt + 1) * 64;
            const unsigned short* gq = gQ + (kt + 1) * 64;
            ra0 = *(const uint4*)(gp + 0);
            ra1 = *(const uint4*)(gp + 8);
            ra2 = *(const uint4*)(gp + 16);
            ra3 = *(const uint4*)(gp + 24);
            rb0 = *(const uint4*)(gq + 0);
            rb1 = *(const uint4*)(gq + 8);
            rb2 = *(const uint4*)(gq + 16);
            rb3 = *(const uint4*)(gq + 24);
        }
        const unsigned short* pbase = sP + cl * LSTR;
        const unsigned short* qbase = sQ + rl * LSTR;
#pragma unroll
        for (int vv = 0; vv < 8; ++vv) {
            uint4 q[8];
#pragma unroll
            for (int w = 0; w < 8; ++w)
                q[w] = *(const uint4*)(qbase + w * 16 * LSTR + vv * 8);
            // p in PAIRS: bounded live set, 16 b128 reads feed 256 SADs
#pragma unroll
            for (int h = 0; h < 4; ++h) {
                uint4 p0 = *(const uint4*)(pbase + (2 * h + 0) * 16 * LSTR + vv * 8);
                uint4 p1 = *(const uint4*)(pbase + (2 * h + 1) * 16 * LSTR + vv * 8);
#pragma unroll
                for (int w = 0; w < 8; ++w) {
                    unsigned a = acc[w][2 * h + 0];
                    a = __builtin_amdgcn_sad_u16(p0.x, q[w].x, a);
                    a = __builtin_amdgcn_sad_u16(p0.y, q[w].y, a);
                    a = __builtin_amdgcn_sad_u16(p0.z, q[w].z, a);
                    a = __builtin_amdgcn_sad_u16(p0.w, q[w].w, a);
                    acc[w][2 * h + 0] = a;
                    unsigned b = acc[w][2 * h + 1];
                    b = __builtin_amdgcn_sad_u16(p1.x, q[w].x, b);
                    b = __builtin_amdgcn_sad_u16(p1.y, q[w].y, b);
                    b = __builtin_amdgcn_sad_u16(p1.z, q[w].z, b);
                    b = __builtin_amdgcn_sad_u16(p1.w, q[w].w, b);
                    acc[w][2 * h + 1] = b;
                }
            }
        }
        if (kt < 15) {
            __syncthreads();   // all waves done reading current tile
            *(uint4*)(lP + 0)  = ra0;
            *(uint4*)(lP + 8)  = ra1;
            *(uint4*)(lP + 16) = ra2;
            *(uint4*)(lP + 24) = ra3;
            *(uint4*)(lQ + 0)  = rb0;
            *(uint4*)(lQ + 8)  = rb1;
            *(uint4*)(lQ + 16) = rb2;
            *(uint4*)(lQ + 24) = rb3;
            __syncthreads();   // staging visible
        }
    }

    float* outp = spart + (size_t)bv * (BSZ * BSZ);
    const float SCL = 1.0f / 65535.0f;
#pragma unroll
    for (int w = 0; w < 8; ++w) {
        size_t jr = (size_t)(bj * TSJ + rl + 16 * w);
#pragma unroll
        for (int u = 0; u < 8; ++u) {
            int ic = bi * TSI + cl + 16 * u;
            outp[jr * BSZ + ic] = (float)acc[w][u] * SCL;
        }
    }
}

// ------- combine v-partials: W = sum parts (direct L1) -----------------------
// K is no longer materialized: sinkhorn computes K = exp2(W*CE) during its
// LDS staging (64 exp2/thread, free). Saves 4 MB write here + 4.3 MB read
// there. Also zero-inits the 3 rotating c-buffers + barrier flags.
__global__ __launch_bounds__(256) void combine_kernel(const float* __restrict__ spart,
                                                      float* __restrict__ wt,
                                                      float* __restrict__ cpart,
                                                      unsigned* __restrict__ flags) {
    if (blockIdx.x == 0 && threadIdx.x < NBLK) flags[threadIdx.x * 32] = 0u;
    if (blockIdx.x < 3) {
        float4 z4; z4.x = z4.y = z4.z = z4.w = 0.f;
        ((float4*)cpart)[blockIdx.x * 256 + threadIdx.x] = z4;  // 3 x 1024 floats
    }
    int idx = blockIdx.x * 256 + threadIdx.x;  // over B*B/4 float4s
    const float4* p0 = (const float4*)spart;
    const int Q = (BSZ * BSZ) / 4;
    float4 a = p0[idx], b = p0[idx + Q], c = p0[idx + 2 * Q], d = p0[idx + 3 * Q];
    float4 w;
    w.x = (a.x + b.x) + (c.x + d.x);
    w.y = (a.y + b.y) + (c.y + d.y);
    w.z = (a.z + b.z) + (c.z + d.z);
    w.w = (a.w + b.w) + (c.w + d.w);
    ((float4*)wt)[idx] = w;
}

// ------- grid barrier v4: all-to-all (no master/go relay hop) -----------------
__device__ inline void grid_barrier(unsigned* flags, unsigned gen) {
    __syncthreads();
    const int t = threadIdx.x;
    if (t == 0)  // RELEASE: flush this block's stores (incl. c-buffer zeros)
        __hip_atomic_store(&flags[blockIdx.x * 32], gen, __ATOMIC_RELEASE, __HIP_MEMORY_SCOPE_AGENT);
    if (t < NBLK) {
        while (__hip_atomic_load(&flags[t * 32], __ATOMIC_RELAXED, __HIP_MEMORY_SCOPE_AGENT) < gen)
            __builtin_amdgcn_s_sleep(1);
    }
    __syncthreads();
    if (t == 0)  // single ACQUIRE: one cache inv for the whole block
        (void)__hip_atomic_load(&flags[0], __ATOMIC_ACQUIRE, __HIP_MEMORY_SCOPE_AGENT);
    __syncthreads();
}

// ---------------- Sinkhorn: a = 1/(K b); b = 1/(K^T a), 20 iters + final sum --
// R24: (a) K computed from W during staging (combine no longer writes kt);
// (b) atomic push STAGGERED: block z sweeps columns starting at z*16 so the
// 32 blocks hit different cachelines of cbuf at any instant (the in-order
// sweep serialized ~32-deep per cacheline at the home L2).
__global__ __launch_bounds__(512) void sinkhorn_kernel(const float* __restrict__ WT,
                                                       float* __restrict__ cpart,
                                                       float* __restrict__ outpart,
                                                       float* __restrict__ out,
                                                       unsigned* __restrict__ flags) {
    __shared__ __align__(16) float k_lds[JPB * KPAD];   // 133,120 B
    __shared__ __align__(16) float a_sh[BSZ];
    __shared__ float b_sh[JPB];
    __shared__ float red[JPB];
    const int z = blockIdx.x;
    const int t = threadIdx.x;
    const int j0 = z * JPB;
    const float CE = -14.426950408889634f;  // -log2(e)/eps, eps=0.1
#pragma unroll
    for (int m = 0; m < 16; ++m) {
        int idx = t + 512 * m;
        int row = idx >> 8;
        int col = (idx & 255) * 4;
        float4 w = *(const float4*)(WT + (size_t)(j0 + row) * BSZ + col);
        float4 k;
        k.x = exp2f(w.x * CE);
        k.y = exp2f(w.y * CE);
        k.z = exp2f(w.z * CE);
        k.w = exp2f(w.w * CE);
        *(float4*)(&k_lds[row * KPAD + col]) = k;
    }
    if (t < JPB) b_sh[t] = 1.0f;
    __syncthreads();
    const int jj = t >> 4;   // 0..31
    const int il = t & 15;
    const int colp = (t + z * 16) & 511;   // staggered column pair index
    unsigned gen = 1u;
    for (int it = 0; it < 20; ++it) {
        float* cbuf = cpart + (size_t)(it % 3) * BSZ;
        float2 s = {0.f, 0.f};
#pragma unroll
        for (int q = 0; q < JPB; ++q) {
            float2 kv = *(const float2*)(&k_lds[q * KPAD + 2 * colp]);
            float bb = b_sh[q];
            s.x += kv.x * bb; s.y += kv.y * bb;
        }
        (void)__hip_atomic_fetch_add(&cbuf[2 * colp],     s.x, __ATOMIC_RELAXED, __HIP_MEMORY_SCOPE_AGENT);
        (void)__hip_atomic_fetch_add(&cbuf[2 * colp + 1], s.y, __ATOMIC_RELAXED, __HIP_MEMORY_SCOPE_AGENT);
        grid_barrier(flags, gen++);
        float2 cv = *(const float2*)(&cbuf[2 * colp]);
        // re-zero own slice of the buffer that iter it+3 will accumulate into
        if (t < 32) cpart[(size_t)((it + 2) % 3) * BSZ + z * 32 + t] = 0.f;
        float2 ar;
        ar.x = 1.0f / cv.x; ar.y = 1.0f / cv.y;
        ((float2*)a_sh)[colp] = ar;
        __syncthreads();
        float sb = 0.f;
#pragma unroll
        for (int m2 = 0; m2 < 16; ++m2) {
            float4 kv = *(const float4*)(&k_lds[jj * KPAD + (il + 16 * m2) * 4]);
            float4 av = ((const float4*)a_sh)[il + 16 * m2];
            sb += (kv.x * av.x + kv.y * av.y) + (kv.z * av.z + kv.w * av.w);
        }
#pragma unroll
        for (int d = 8; d >= 1; d >>= 1) sb += __shfl_down(sb, d, 16);
        if (il == 0) b_sh[jj] = 1.0f / sb;
        __syncthreads();
    }
    {
        const float4* wrow = (const float4*)(WT + (size_t)(j0 + jj) * BSZ);
        float sb = 0.f;
#pragma unroll 4
        for (int m2 = 0; m2 < 16; ++m2) {
            float4 kv = *(const float4*)(&k_lds[jj * KPAD + (il + 16 * m2) * 4]);
            float4 wv = wrow[il + 16 * m2];
            float4 av = ((const float4*)a_sh)[il + 16 * m2];
            sb += (av.x * kv.x * wv.x + av.y * kv.y * wv.y) +
                  (av.z * kv.z * wv.z + av.w * kv.w * wv.w);
        }
#pragma unroll
        for (int d = 8; d >= 1; d >>= 1) sb += __shfl_down(sb, d, 16);
        if (il == 0) red[jj] = sb * b_sh[jj];
        __syncthreads();
        if (t == 0) {
            float ss = 0.f;
#pragma unroll
            for (int q = 0; q < JPB; ++q) ss += red[q];
            outpart[z] = ss;
        }
    }
    grid_barrier(flags, gen++);
    if (z == 0 && t == 0) {
        float ss = 0.f;
        for (int q = 0; q < NBLK; ++q) ss += outpart[q];
        out[0] = 0.001f * ss;
    }
}

extern "C" void kernel_launch(void* const* d_in, const int* in_sizes, int n_in,
                              void* d_out, int out_size, void* d_ws, size_t ws_size,
                              hipStream_t stream) {
    const float* ys = (const float*)d_in[0];
    const float* yt = (const float*)d_in[1];
    float* ws = (float*)d_ws;
    unsigned short* psh = (unsigned short*)ws;                        // 1024x4096 u16
    unsigned short* pth = (unsigned short*)(ws + 2ull * 1024 * 1024); // 1024x4096 u16
    float* spart   = ws + 4ull * 1024 * 1024;              // 4 x 1M floats
    float* wt      = spart + 4ull * BSZ * BSZ;             // 1M
    float* kt      = wt + (size_t)BSZ * BSZ;               // 1M (unused now)
    float* cpart   = kt + (size_t)BSZ * BSZ;               // 3 x 1024 used
    float* outpart = cpart + 2ull * NBLK * BSZ;            // 32 (+pad)
    unsigned* flags = (unsigned*)(outpart + 128);          // NBLK x 32 uints
    float* outp    = (float*)d_out;

    softmax_kernel<<<dim3(2 * BSZ), dim3(256), 0, stream>>>(ys, yt, psh, pth);
    cdist_kernel<<<dim3(8, 8, 4), dim3(256), 0, stream>>>(psh, pth, spart);
    combine_kernel<<<dim3((BSZ * BSZ / 4) / 256), dim3(256), 0, stream>>>(spart, wt, cpart, flags);

    void* args[] = {(void*)&wt, (void*)&cpart, (void*)&outpart, (void*)&outp, (void*)&flags};
    (void)hipLaunchCooperativeKernel((void*)sinkhorn_kernel, dim3(NBLK), dim3(512), args, 0, stream);
}

// Round 10
// 281.088 us; speedup vs baseline: 1.8455x; 1.8455x over previous
//
#include <hip/hip_runtime.h>
#include <hip/hip_fp16.h>

#define BSZ 1024   // B
#define VSZ 4096   // V
#define NBLK 32    // sinkhorn blocks (32 j-rows each, 512 threads)
#define JPB 32     // j's per sinkhorn block
#define KPAD 1040  // LDS row stride for K (1024 + 16 floats)

// ---------------- softmax(y/2) row-wise, writes u16 fixed-point probs --------
__global__ __launch_bounds__(256) void softmax_kernel(const float* __restrict__ ys,
                                                      const float* __restrict__ yt,
                                                      unsigned short* __restrict__ ps,
                                                      unsigned short* __restrict__ pt) {
    int row = blockIdx.x;
    const float* src;
    unsigned short* dst;
    if (row < BSZ) { src = ys + (size_t)row * VSZ;         dst = ps + (size_t)row * VSZ; }
    else           { src = yt + (size_t)(row - BSZ) * VSZ; dst = pt + (size_t)(row - BSZ) * VSZ; }
    int t = threadIdx.x;
    float4 v[4];
    float m = -1e30f;
#pragma unroll
    for (int k = 0; k < 4; ++k) {
        v[k] = ((const float4*)src)[t + 256 * k];
        m = fmaxf(m, fmaxf(fmaxf(v[k].x, v[k].y), fmaxf(v[k].z, v[k].w)));
    }
#pragma unroll
    for (int d = 32; d >= 1; d >>= 1) m = fmaxf(m, __shfl_down(m, d));
    __shared__ float sred[4];
    __shared__ float sred2[4];
    int lane = t & 63, wid = t >> 6;
    if (lane == 0) sred[wid] = m;
    __syncthreads();
    m = fmaxf(fmaxf(sred[0], sred[1]), fmaxf(sred[2], sred[3]));
    const float C = 0.7213475204444817f;  // 0.5 * log2(e)  (T = 2)
    float s = 0.f;
#pragma unroll
    for (int k = 0; k < 4; ++k) {
        v[k].x = exp2f((v[k].x - m) * C);
        v[k].y = exp2f((v[k].y - m) * C);
        v[k].z = exp2f((v[k].z - m) * C);
        v[k].w = exp2f((v[k].w - m) * C);
        s += (v[k].x + v[k].y) + (v[k].z + v[k].w);
    }
#pragma unroll
    for (int d = 32; d >= 1; d >>= 1) s += __shfl_down(s, d);
    if (lane == 0) sred2[wid] = s;
    __syncthreads();
    s = (sred2[0] + sred2[1]) + (sred2[2] + sred2[3]);
    float inv = 65535.0f / s;  // fold quantization scale into the normalizer
#pragma unroll
    for (int k = 0; k < 4; ++k) {
        union { unsigned short h[4]; uint2 u; } o;
        o.h[0] = (unsigned short)__float2uint_rn(fminf(v[k].x * inv, 65535.0f));
        o.h[1] = (unsigned short)__float2uint_rn(fminf(v[k].y * inv, 65535.0f));
        o.h[2] = (unsigned short)__float2uint_rn(fminf(v[k].z * inv, 65535.0f));
        o.h[3] = (unsigned short)__float2uint_rn(fminf(v[k].w * inv, 65535.0f));
        ((uint2*)dst)[t + 256 * k] = o.u;
    }
}

// ---------------- W-partial: WT[j][i] = sum_v |ps[i,v] - pt[j,v]| ------------
// R25 = R23 champion, verbatim. The 8x8 DS-halving path is CLOSED: it spilled
// at VGPR=256 twice (R17, R24: acc64+q32+prefetch32 > file even with pairs).
// R23 config: 128x64 tile, 256 threads, 8x4 acc, SINGLE LDS buffer 27.6KB ->
// 4 blocks/CU at launch_bounds(256,4) (128-VGPR pin is sufficient: live ~80),
// transient staging regs (load->sync->ds_write->sync->compute). Cross-block
// overlap (m114) hides HBM latency + overlaps DS with VALU. Measured R8:
// cdist < 97.7us, total 284.8us, WRITE_SIZE 16.4MB clean.
#define TSI 128  // i-tile
#define TSJ 64   // j-tile
#define LSTR 72  // u16 row stride (144 B): 2-way bank aliasing -> free (m136)

__global__ __launch_bounds__(256, 4) void cdist_kernel(const unsigned short* __restrict__ psh,
                                                       const unsigned short* __restrict__ pth,
                                                       float* __restrict__ spart) {
    __shared__ unsigned short sP[TSI * LSTR];   // 18,432 B
    __shared__ unsigned short sQ[TSJ * LSTR];   //  9,216 B  (27.6 KB total)
    const int bi = blockIdx.x;   // 8  i-panels
    const int bj = blockIdx.y;   // 16 j-panels
    const int bv = blockIdx.z;   // 4  v-chunks
    const int t = threadIdx.x;
    const int cl = t & 15;   // i-lane (16)
    const int rl = t >> 4;   // j-lane (16)

    // staging: P: thread t -> row t>>1 (128 rows), half (t&1)*64B (4 uint4).
    //          Q: thread t -> row t>>2 (64 rows), quarter (t&3)*32B (2 uint4).
    const int pr = t >> 1, pc = (t & 1) * 32;
    const int qr = t >> 2, qc = (t & 3) * 16;
    const unsigned short* gP = psh + (size_t)(bi * TSI + pr) * VSZ + bv * 1024 + pc;
    const unsigned short* gQ = pth + (size_t)(bj * TSJ + qr) * VSZ + bv * 1024 + qc;
    unsigned short* lP = &sP[pr * LSTR + pc];
    unsigned short* lQ = &sQ[qr * LSTR + qc];

    unsigned acc[4][8];
#pragma unroll
    for (int w = 0; w < 4; ++w)
#pragma unroll
        for (int u = 0; u < 8; ++u) acc[w][u] = 0u;

    for (int kt = 0; kt < 16; ++kt) {
        // load this kt's tile into transient regs (issued before the barrier;
        // latency overlaps other waves' compute + barrier wait)
        const unsigned short* gp = gP + kt * 64;
        const unsigned short* gq = gQ + kt * 64;
        uint4 a0 = *(const uint4*)(gp + 0);
        uint4 a1 = *(const uint4*)(gp + 8);
        uint4 a2 = *(const uint4*)(gp + 16);
        uint4 a3 = *(const uint4*)(gp + 24);
        uint4 b0 = *(const uint4*)(gq + 0);
        uint4 b1 = *(const uint4*)(gq + 8);
        __syncthreads();   // all waves finished reading previous tile
        *(uint4*)(lP + 0)  = a0;
        *(uint4*)(lP + 8)  = a1;
        *(uint4*)(lP + 16) = a2;
        *(uint4*)(lP + 24) = a3;
        *(uint4*)(lQ + 0)  = b0;
        *(uint4*)(lQ + 8)  = b1;
        __syncthreads();   // staging visible
        const unsigned short* pbase = sP + cl * LSTR;
        const unsigned short* qbase = sQ + rl * LSTR;
#pragma unroll
        for (int vv = 0; vv < 8; ++vv) {
            uint4 q[4];
#pragma unroll
            for (int w = 0; w < 4; ++w)
                q[w] = *(const uint4*)(qbase + w * 16 * LSTR + vv * 8);
            // p loaded in PAIRS (8 regs live) -> bounded register pressure
#pragma unroll
            for (int h = 0; h < 4; ++h) {
                uint4 p0 = *(const uint4*)(pbase + (2 * h + 0) * 16 * LSTR + vv * 8);
                uint4 p1 = *(const uint4*)(pbase + (2 * h + 1) * 16 * LSTR + vv * 8);
#pragma unroll
                for (int w = 0; w < 4; ++w) {
                    unsigned a = acc[w][2 * h + 0];
                    a = __builtin_amdgcn_sad_u16(p0.x, q[w].x, a);
                    a = __builtin_amdgcn_sad_u16(p0.y, q[w].y, a);
                    a = __builtin_amdgcn_sad_u16(p0.z, q[w].z, a);
                    a = __builtin_amdgcn_sad_u16(p0.w, q[w].w, a);
                    acc[w][2 * h + 0] = a;
                    unsigned b = acc[w][2 * h + 1];
                    b = __builtin_amdgcn_sad_u16(p1.x, q[w].x, b);
                    b = __builtin_amdgcn_sad_u16(p1.y, q[w].y, b);
                    b = __builtin_amdgcn_sad_u16(p1.z, q[w].z, b);
                    b = __builtin_amdgcn_sad_u16(p1.w, q[w].w, b);
                    acc[w][2 * h + 1] = b;
                }
            }
        }
    }

    float* outp = spart + (size_t)bv * (BSZ * BSZ);
    const float SCL = 1.0f / 65535.0f;
#pragma unroll
    for (int w = 0; w < 4; ++w) {
        size_t jr = (size_t)(bj * TSJ + rl + 16 * w);
#pragma unroll
        for (int u = 0; u < 8; ++u) {
            int ic = bi * TSI + cl + 16 * u;
            outp[jr * BSZ + ic] = (float)acc[w][u] * SCL;
        }
    }
}

// ------- combine v-partials: W = sum parts (direct L1) -----------------------
// K is not materialized: sinkhorn computes K = exp2(W*CE) during its LDS
// staging. Also zero-inits the 3 rotating c-buffers + barrier flags.
__global__ __launch_bounds__(256) void combine_kernel(const float* __restrict__ spart,
                                                      float* __restrict__ wt,
                                                      float* __restrict__ cpart,
                                                      unsigned* __restrict__ flags) {
    if (blockIdx.x == 0 && threadIdx.x < NBLK) flags[threadIdx.x * 32] = 0u;
    if (blockIdx.x < 3) {
        float4 z4; z4.x = z4.y = z4.z = z4.w = 0.f;
        ((float4*)cpart)[blockIdx.x * 256 + threadIdx.x] = z4;  // 3 x 1024 floats
    }
    int idx = blockIdx.x * 256 + threadIdx.x;  // over B*B/4 float4s
    const float4* p0 = (const float4*)spart;
    const int Q = (BSZ * BSZ) / 4;
    float4 a = p0[idx], b = p0[idx + Q], c = p0[idx + 2 * Q], d = p0[idx + 3 * Q];
    float4 w;
    w.x = (a.x + b.x) + (c.x + d.x);
    w.y = (a.y + b.y) + (c.y + d.y);
    w.z = (a.z + b.z) + (c.z + d.z);
    w.w = (a.w + b.w) + (c.w + d.w);
    ((float4*)wt)[idx] = w;
}

// ------- grid barrier v4: all-to-all (no master/go relay hop) -----------------
__device__ inline void grid_barrier(unsigned* flags, unsigned gen) {
    __syncthreads();
    const int t = threadIdx.x;
    if (t == 0)  // RELEASE: flush this block's stores (incl. c-buffer zeros)
        __hip_atomic_store(&flags[blockIdx.x * 32], gen, __ATOMIC_RELEASE, __HIP_MEMORY_SCOPE_AGENT);
    if (t < NBLK) {
        while (__hip_atomic_load(&flags[t * 32], __ATOMIC_RELAXED, __HIP_MEMORY_SCOPE_AGENT) < gen)
            __builtin_amdgcn_s_sleep(1);
    }
    __syncthreads();
    if (t == 0)  // single ACQUIRE: one cache inv for the whole block
        (void)__hip_atomic_load(&flags[0], __ATOMIC_ACQUIRE, __HIP_MEMORY_SCOPE_AGENT);
    __syncthreads();
}

// ---------------- Sinkhorn: a = 1/(K b); b = 1/(K^T a), 20 iters + final sum --
// R24 version kept: K computed from W during staging; atomic push STAGGERED
// (block z starts at column pair z*16) so 32 blocks hit different cachelines.
__global__ __launch_bounds__(512) void sinkhorn_kernel(const float* __restrict__ WT,
                                                       float* __restrict__ cpart,
                                                       float* __restrict__ outpart,
                                                       float* __restrict__ out,
                                                       unsigned* __restrict__ flags) {
    __shared__ __align__(16) float k_lds[JPB * KPAD];   // 133,120 B
    __shared__ __align__(16) float a_sh[BSZ];
    __shared__ float b_sh[JPB];
    __shared__ float red[JPB];
    const int z = blockIdx.x;
    const int t = threadIdx.x;
    const int j0 = z * JPB;
    const float CE = -14.426950408889634f;  // -log2(e)/eps, eps=0.1
#pragma unroll
    for (int m = 0; m < 16; ++m) {
        int idx = t + 512 * m;
        int row = idx >> 8;
        int col = (idx & 255) * 4;
        float4 w = *(const float4*)(WT + (size_t)(j0 + row) * BSZ + col);
        float4 k;
        k.x = exp2f(w.x * CE);
        k.y = exp2f(w.y * CE);
        k.z = exp2f(w.z * CE);
        k.w = exp2f(w.w * CE);
        *(float4*)(&k_lds[row * KPAD + col]) = k;
    }
    if (t < JPB) b_sh[t] = 1.0f;
    __syncthreads();
    const int jj = t >> 4;   // 0..31
    const int il = t & 15;
    const int colp = (t + z * 16) & 511;   // staggered column pair index
    unsigned gen = 1u;
    for (int it = 0; it < 20; ++it) {
        float* cbuf = cpart + (size_t)(it % 3) * BSZ;
        float2 s = {0.f, 0.f};
#pragma unroll
        for (int q = 0; q < JPB; ++q) {
            float2 kv = *(const float2*)(&k_lds[q * KPAD + 2 * colp]);
            float bb = b_sh[q];
            s.x += kv.x * bb; s.y += kv.y * bb;
        }
        (void)__hip_atomic_fetch_add(&cbuf[2 * colp],     s.x, __ATOMIC_RELAXED, __HIP_MEMORY_SCOPE_AGENT);
        (void)__hip_atomic_fetch_add(&cbuf[2 * colp + 1], s.y, __ATOMIC_RELAXED, __HIP_MEMORY_SCOPE_AGENT);
        grid_barrier(flags, gen++);
        float2 cv = *(const float2*)(&cbuf[2 * colp]);
        // re-zero own slice of the buffer that iter it+3 will accumulate into
        if (t < 32) cpart[(size_t)((it + 2) % 3) * BSZ + z * 32 + t] = 0.f;
        float2 ar;
        ar.x = 1.0f / cv.x; ar.y = 1.0f / cv.y;
        ((float2*)a_sh)[colp] = ar;
        __syncthreads();
        float sb = 0.f;
#pragma unroll
        for (int m2 = 0; m2 < 16; ++m2) {
            float4 kv = *(const float4*)(&k_lds[jj * KPAD + (il + 16 * m2) * 4]);
            float4 av = ((const float4*)a_sh)[il + 16 * m2];
            sb += (kv.x * av.x + kv.y * av.y) + (kv.z * av.z + kv.w * av.w);
        }
#pragma unroll
        for (int d = 8; d >= 1; d >>= 1) sb += __shfl_down(sb, d, 16);
        if (il == 0) b_sh[jj] = 1.0f / sb;
        __syncthreads();
    }
    {
        const float4* wrow = (const float4*)(WT + (size_t)(j0 + jj) * BSZ);
        float sb = 0.f;
#pragma unroll 4
        for (int m2 = 0; m2 < 16; ++m2) {
            float4 kv = *(const float4*)(&k_lds[jj * KPAD + (il + 16 * m2) * 4]);
            float4 wv = wrow[il + 16 * m2];
            float4 av = ((const float4*)a_sh)[il + 16 * m2];
            sb += (av.x * kv.x * wv.x + av.y * kv.y * wv.y) +
                  (av.z * kv.z * wv.z + av.w * kv.w * wv.w);
        }
#pragma unroll
        for (int d = 8; d >= 1; d >>= 1) sb += __shfl_down(sb, d, 16);
        if (il == 0) red[jj] = sb * b_sh[jj];
        __syncthreads();
        if (t == 0) {
            float ss = 0.f;
#pragma unroll
            for (int q = 0; q < JPB; ++q) ss += red[q];
            outpart[z] = ss;
        }
    }
    grid_barrier(flags, gen++);
    if (z == 0 && t == 0) {
        float ss = 0.f;
        for (int q = 0; q < NBLK; ++q) ss += outpart[q];
        out[0] = 0.001f * ss;
    }
}

extern "C" void kernel_launch(void* const* d_in, const int* in_sizes, int n_in,
                              void* d_out, int out_size, void* d_ws, size_t ws_size,
                              hipStream_t stream) {
    const float* ys = (const float*)d_in[0];
    const float* yt = (const float*)d_in[1];
    float* ws = (float*)d_ws;
    unsigned short* psh = (unsigned short*)ws;                        // 1024x4096 u16
    unsigned short* pth = (unsigned short*)(ws + 2ull * 1024 * 1024); // 1024x4096 u16
    float* spart   = ws + 4ull * 1024 * 1024;              // 4 x 1M floats
    float* wt      = spart + 4ull * BSZ * BSZ;             // 1M
    float* kt      = wt + (size_t)BSZ * BSZ;               // 1M (unused now)
    float* cpart   = kt + (size_t)BSZ * BSZ;               // 3 x 1024 used
    float* outpart = cpart + 2ull * NBLK * BSZ;            // 32 (+pad)
    unsigned* flags = (unsigned*)(outpart + 128);          // NBLK x 32 uints
    float* outp    = (float*)d_out;

    softmax_kernel<<<dim3(2 * BSZ), dim3(256), 0, stream>>>(ys, yt, psh, pth);
    cdist_kernel<<<dim3(8, 16, 4), dim3(256), 0, stream>>>(psh, pth, spart);
    combine_kernel<<<dim3((BSZ * BSZ / 4) / 256), dim3(256), 0, stream>>>(spart, wt, cpart, flags);

    void* args[] = {(void*)&wt, (void*)&cpart, (void*)&outpart, (void*)&outp, (void*)&flags};
    (void)hipLaunchCooperativeKernel((void*)sinkhorn_kernel, dim3(NBLK), dim3(512), args, 0, stream);
}

// Round 11
// 259.217 us; speedup vs baseline: 2.0012x; 1.0844x over previous
//
#include <hip/hip_runtime.h>
#include <hip/hip_fp16.h>

#define BSZ 1024   // B
#define VSZ 4096   // V
#define NBLK 32    // sinkhorn blocks (32 j-rows each, 512 threads)
#define JPB 32     // j's per sinkhorn block
#define KPAD 1040  // LDS row stride for K (1024 + 16 floats)

// ---------------- softmax(y/2) row-wise, writes u16 fixed-point probs --------
// Also takes over cpart/flags zero-init from the deleted combine kernel.
__global__ __launch_bounds__(256) void softmax_kernel(const float* __restrict__ ys,
                                                      const float* __restrict__ yt,
                                                      unsigned short* __restrict__ ps,
                                                      unsigned short* __restrict__ pt,
                                                      float* __restrict__ cpart,
                                                      unsigned* __restrict__ flags) {
    if (blockIdx.x == 0 && threadIdx.x < NBLK) flags[threadIdx.x * 32] = 0u;
    if (blockIdx.x < 3) {
        float4 z4; z4.x = z4.y = z4.z = z4.w = 0.f;
        ((float4*)cpart)[blockIdx.x * 256 + threadIdx.x] = z4;  // 3 x 1024 floats
    }
    int row = blockIdx.x;
    const float* src;
    unsigned short* dst;
    if (row < BSZ) { src = ys + (size_t)row * VSZ;         dst = ps + (size_t)row * VSZ; }
    else           { src = yt + (size_t)(row - BSZ) * VSZ; dst = pt + (size_t)(row - BSZ) * VSZ; }
    int t = threadIdx.x;
    float4 v[4];
    float m = -1e30f;
#pragma unroll
    for (int k = 0; k < 4; ++k) {
        v[k] = ((const float4*)src)[t + 256 * k];
        m = fmaxf(m, fmaxf(fmaxf(v[k].x, v[k].y), fmaxf(v[k].z, v[k].w)));
    }
#pragma unroll
    for (int d = 32; d >= 1; d >>= 1) m = fmaxf(m, __shfl_down(m, d));
    __shared__ float sred[4];
    __shared__ float sred2[4];
    int lane = t & 63, wid = t >> 6;
    if (lane == 0) sred[wid] = m;
    __syncthreads();
    m = fmaxf(fmaxf(sred[0], sred[1]), fmaxf(sred[2], sred[3]));
    const float C = 0.7213475204444817f;  // 0.5 * log2(e)  (T = 2)
    float s = 0.f;
#pragma unroll
    for (int k = 0; k < 4; ++k) {
        v[k].x = exp2f((v[k].x - m) * C);
        v[k].y = exp2f((v[k].y - m) * C);
        v[k].z = exp2f((v[k].z - m) * C);
        v[k].w = exp2f((v[k].w - m) * C);
        s += (v[k].x + v[k].y) + (v[k].z + v[k].w);
    }
#pragma unroll
    for (int d = 32; d >= 1; d >>= 1) s += __shfl_down(s, d);
    if (lane == 0) sred2[wid] = s;
    __syncthreads();
    s = (sred2[0] + sred2[1]) + (sred2[2] + sred2[3]);
    float inv = 65535.0f / s;  // fold quantization scale into the normalizer
#pragma unroll
    for (int k = 0; k < 4; ++k) {
        union { unsigned short h[4]; uint2 u; } o;
        o.h[0] = (unsigned short)__float2uint_rn(fminf(v[k].x * inv, 65535.0f));
        o.h[1] = (unsigned short)__float2uint_rn(fminf(v[k].y * inv, 65535.0f));
        o.h[2] = (unsigned short)__float2uint_rn(fminf(v[k].z * inv, 65535.0f));
        o.h[3] = (unsigned short)__float2uint_rn(fminf(v[k].w * inv, 65535.0f));
        ((uint2*)dst)[t + 256 * k] = o.u;
    }
}

// ---------------- W-partial: WT[j][i] = sum_v |ps[i,v] - pt[j,v]| ------------
// R23 champion, UNTOUCHED (8x8 path closed: spilled at VGPR=256 twice).
// 128x64 tile, 256 threads, 8x4 acc, single LDS buffer 27.6KB, transient
// staging regs, launch_bounds(256,4): live ~80 VGPR under the 128 pin.
#define TSI 128  // i-tile
#define TSJ 64   // j-tile
#define LSTR 72  // u16 row stride (144 B): 2-way bank aliasing -> free (m136)

__global__ __launch_bounds__(256, 4) void cdist_kernel(const unsigned short* __restrict__ psh,
                                                       const unsigned short* __restrict__ pth,
                                                       float* __restrict__ spart) {
    __shared__ unsigned short sP[TSI * LSTR];   // 18,432 B
    __shared__ unsigned short sQ[TSJ * LSTR];   //  9,216 B  (27.6 KB total)
    const int bi = blockIdx.x;   // 8  i-panels
    const int bj = blockIdx.y;   // 16 j-panels
    const int bv = blockIdx.z;   // 4  v-chunks
    const int t = threadIdx.x;
    const int cl = t & 15;   // i-lane (16)
    const int rl = t >> 4;   // j-lane (16)

    const int pr = t >> 1, pc = (t & 1) * 32;
    const int qr = t >> 2, qc = (t & 3) * 16;
    const unsigned short* gP = psh + (size_t)(bi * TSI + pr) * VSZ + bv * 1024 + pc;
    const unsigned short* gQ = pth + (size_t)(bj * TSJ + qr) * VSZ + bv * 1024 + qc;
    unsigned short* lP = &sP[pr * LSTR + pc];
    unsigned short* lQ = &sQ[qr * LSTR + qc];

    unsigned acc[4][8];
#pragma unroll
    for (int w = 0; w < 4; ++w)
#pragma unroll
        for (int u = 0; u < 8; ++u) acc[w][u] = 0u;

    for (int kt = 0; kt < 16; ++kt) {
        const unsigned short* gp = gP + kt * 64;
        const unsigned short* gq = gQ + kt * 64;
        uint4 a0 = *(const uint4*)(gp + 0);
        uint4 a1 = *(const uint4*)(gp + 8);
        uint4 a2 = *(const uint4*)(gp + 16);
        uint4 a3 = *(const uint4*)(gp + 24);
        uint4 b0 = *(const uint4*)(gq + 0);
        uint4 b1 = *(const uint4*)(gq + 8);
        __syncthreads();   // all waves finished reading previous tile
        *(uint4*)(lP + 0)  = a0;
        *(uint4*)(lP + 8)  = a1;
        *(uint4*)(lP + 16) = a2;
        *(uint4*)(lP + 24) = a3;
        *(uint4*)(lQ + 0)  = b0;
        *(uint4*)(lQ + 8)  = b1;
        __syncthreads();   // staging visible
        const unsigned short* pbase = sP + cl * LSTR;
        const unsigned short* qbase = sQ + rl * LSTR;
#pragma unroll
        for (int vv = 0; vv < 8; ++vv) {
            uint4 q[4];
#pragma unroll
            for (int w = 0; w < 4; ++w)
                q[w] = *(const uint4*)(qbase + w * 16 * LSTR + vv * 8);
#pragma unroll
            for (int h = 0; h < 4; ++h) {
                uint4 p0 = *(const uint4*)(pbase + (2 * h + 0) * 16 * LSTR + vv * 8);
                uint4 p1 = *(const uint4*)(pbase + (2 * h + 1) * 16 * LSTR + vv * 8);
#pragma unroll
                for (int w = 0; w < 4; ++w) {
                    unsigned a = acc[w][2 * h + 0];
                    a = __builtin_amdgcn_sad_u16(p0.x, q[w].x, a);
                    a = __builtin_amdgcn_sad_u16(p0.y, q[w].y, a);
                    a = __builtin_amdgcn_sad_u16(p0.z, q[w].z, a);
                    a = __builtin_amdgcn_sad_u16(p0.w, q[w].w, a);
                    acc[w][2 * h + 0] = a;
                    unsigned b = acc[w][2 * h + 1];
                    b = __builtin_amdgcn_sad_u16(p1.x, q[w].x, b);
                    b = __builtin_amdgcn_sad_u16(p1.y, q[w].y, b);
                    b = __builtin_amdgcn_sad_u16(p1.z, q[w].z, b);
                    b = __builtin_amdgcn_sad_u16(p1.w, q[w].w, b);
                    acc[w][2 * h + 1] = b;
                }
            }
        }
    }

    float* outp = spart + (size_t)bv * (BSZ * BSZ);
    const float SCL = 1.0f / 65535.0f;
#pragma unroll
    for (int w = 0; w < 4; ++w) {
        size_t jr = (size_t)(bj * TSJ + rl + 16 * w);
#pragma unroll
        for (int u = 0; u < 8; ++u) {
            int ic = bi * TSI + cl + 16 * u;
            outp[jr * BSZ + ic] = (float)acc[w][u] * SCL;
        }
    }
}

// ------- grid barrier: all-to-all flag barrier (no cooperative API needed) ---
__device__ inline void grid_barrier(unsigned* flags, unsigned gen) {
    __syncthreads();
    const int t = threadIdx.x;
    if (t == 0)  // RELEASE: flush this block's stores
        __hip_atomic_store(&flags[blockIdx.x * 32], gen, __ATOMIC_RELEASE, __HIP_MEMORY_SCOPE_AGENT);
    if (t < NBLK) {
        while (__hip_atomic_load(&flags[t * 32], __ATOMIC_RELAXED, __HIP_MEMORY_SCOPE_AGENT) < gen)
            __builtin_amdgcn_s_sleep(1);
    }
    __syncthreads();
    if (t == 0)  // single ACQUIRE: one cache inv for the whole block
        (void)__hip_atomic_load(&flags[0], __ATOMIC_ACQUIRE, __HIP_MEMORY_SCOPE_AGENT);
    __syncthreads();
}

// ---------------- Sinkhorn: a = 1/(K b); b = 1/(K^T a), 20 iters + final sum --
// R26: absorbs the combine kernel. Staging reads the 4 spart v-partials
// directly (sum -> W -> exp2 -> k_lds); the final sum re-reads spart for W
// rows. 32 blocks are trivially co-resident on 256 CUs -> launched as a
// REGULAR kernel (custom flag barrier never needed the cooperative API;
// hipLaunchCooperativeKernel carries the big launch overhead).
// Atomic push is staggered (block z starts at column pair z*16).
__global__ __launch_bounds__(512) void sinkhorn_kernel(const float* __restrict__ spart,
                                                       float* __restrict__ cpart,
                                                       float* __restrict__ outpart,
                                                       float* __restrict__ out,
                                                       unsigned* __restrict__ flags) {
    __shared__ __align__(16) float k_lds[JPB * KPAD];   // 133,120 B
    __shared__ __align__(16) float a_sh[BSZ];
    __shared__ float b_sh[JPB];
    __shared__ float red[JPB];
    const int z = blockIdx.x;
    const int t = threadIdx.x;
    const int j0 = z * JPB;
    const int M = BSZ * BSZ;
    const float CE = -14.426950408889634f;  // -log2(e)/eps, eps=0.1
#pragma unroll
    for (int m = 0; m < 16; ++m) {
        int idx = t + 512 * m;
        int row = idx >> 8;
        int col = (idx & 255) * 4;
        size_t off = (size_t)(j0 + row) * BSZ + col;
        float4 w0 = *(const float4*)(spart + off);
        float4 w1 = *(const float4*)(spart + off + M);
        float4 w2 = *(const float4*)(spart + off + 2 * M);
        float4 w3 = *(const float4*)(spart + off + 3 * M);
        float4 k;
        k.x = exp2f(((w0.x + w1.x) + (w2.x + w3.x)) * CE);
        k.y = exp2f(((w0.y + w1.y) + (w2.y + w3.y)) * CE);
        k.z = exp2f(((w0.z + w1.z) + (w2.z + w3.z)) * CE);
        k.w = exp2f(((w0.w + w1.w) + (w2.w + w3.w)) * CE);
        *(float4*)(&k_lds[row * KPAD + col]) = k;
    }
    if (t < JPB) b_sh[t] = 1.0f;
    __syncthreads();
    const int jj = t >> 4;   // 0..31
    const int il = t & 15;
    const int colp = (t + z * 16) & 511;   // staggered column pair index
    unsigned gen = 1u;
    for (int it = 0; it < 20; ++it) {
        float* cbuf = cpart + (size_t)(it % 3) * BSZ;
        float2 s = {0.f, 0.f};
#pragma unroll
        for (int q = 0; q < JPB; ++q) {
            float2 kv = *(const float2*)(&k_lds[q * KPAD + 2 * colp]);
            float bb = b_sh[q];
            s.x += kv.x * bb; s.y += kv.y * bb;
        }
        (void)__hip_atomic_fetch_add(&cbuf[2 * colp],     s.x, __ATOMIC_RELAXED, __HIP_MEMORY_SCOPE_AGENT);
        (void)__hip_atomic_fetch_add(&cbuf[2 * colp + 1], s.y, __ATOMIC_RELAXED, __HIP_MEMORY_SCOPE_AGENT);
        grid_barrier(flags, gen++);
        float2 cv = *(const float2*)(&cbuf[2 * colp]);
        // re-zero own slice of the buffer that iter it+3 will accumulate into
        if (t < 32) cpart[(size_t)((it + 2) % 3) * BSZ + z * 32 + t] = 0.f;
        float2 ar;
        ar.x = 1.0f / cv.x; ar.y = 1.0f / cv.y;
        ((float2*)a_sh)[colp] = ar;
        __syncthreads();
        float sb = 0.f;
#pragma unroll
        for (int m2 = 0; m2 < 16; ++m2) {
            float4 kv = *(const float4*)(&k_lds[jj * KPAD + (il + 16 * m2) * 4]);
            float4 av = ((const float4*)a_sh)[il + 16 * m2];
            sb += (kv.x * av.x + kv.y * av.y) + (kv.z * av.z + kv.w * av.w);
        }
#pragma unroll
        for (int d = 8; d >= 1; d >>= 1) sb += __shfl_down(sb, d, 16);
        if (il == 0) b_sh[jj] = 1.0f / sb;
        __syncthreads();
    }
    {
        const float* wbase = spart + (size_t)(j0 + jj) * BSZ;
        float sb = 0.f;
#pragma unroll 4
        for (int m2 = 0; m2 < 16; ++m2) {
            int c4 = (il + 16 * m2) * 4;
            float4 kv = *(const float4*)(&k_lds[jj * KPAD + c4]);
            float4 av = ((const float4*)a_sh)[il + 16 * m2];
            float4 wa = *(const float4*)(wbase + c4);
            float4 wb = *(const float4*)(wbase + c4 + M);
            float4 wc = *(const float4*)(wbase + c4 + 2 * M);
            float4 wd = *(const float4*)(wbase + c4 + 3 * M);
            float4 wv;
            wv.x = (wa.x + wb.x) + (wc.x + wd.x);
            wv.y = (wa.y + wb.y) + (wc.y + wd.y);
            wv.z = (wa.z + wb.z) + (wc.z + wd.z);
            wv.w = (wa.w + wb.w) + (wc.w + wd.w);
            sb += (av.x * kv.x * wv.x + av.y * kv.y * wv.y) +
                  (av.z * kv.z * wv.z + av.w * kv.w * wv.w);
        }
#pragma unroll
        for (int d = 8; d >= 1; d >>= 1) sb += __shfl_down(sb, d, 16);
        if (il == 0) red[jj] = sb * b_sh[jj];
        __syncthreads();
        if (t == 0) {
            float ss = 0.f;
#pragma unroll
            for (int q = 0; q < JPB; ++q) ss += red[q];
            outpart[z] = ss;
        }
    }
    grid_barrier(flags, gen++);
    if (z == 0 && t == 0) {
        float ss = 0.f;
        for (int q = 0; q < NBLK; ++q) ss += outpart[q];
        out[0] = 0.001f * ss;
    }
}

extern "C" void kernel_launch(void* const* d_in, const int* in_sizes, int n_in,
                              void* d_out, int out_size, void* d_ws, size_t ws_size,
                              hipStream_t stream) {
    const float* ys = (const float*)d_in[0];
    const float* yt = (const float*)d_in[1];
    float* ws = (float*)d_ws;
    unsigned short* psh = (unsigned short*)ws;                        // 1024x4096 u16
    unsigned short* pth = (unsigned short*)(ws + 2ull * 1024 * 1024); // 1024x4096 u16
    float* spart   = ws + 4ull * 1024 * 1024;              // 4 x 1M floats
    float* wt      = spart + 4ull * BSZ * BSZ;             // 1M (unused)
    float* kt      = wt + (size_t)BSZ * BSZ;               // 1M (unused)
    float* cpart   = kt + (size_t)BSZ * BSZ;               // 3 x 1024 used
    float* outpart = cpart + 2ull * NBLK * BSZ;            // 32 (+pad)
    unsigned* flags = (unsigned*)(outpart + 128);          // NBLK x 32 uints
    float* outp    = (float*)d_out;

    softmax_kernel<<<dim3(2 * BSZ), dim3(256), 0, stream>>>(ys, yt, psh, pth, cpart, flags);
    cdist_kernel<<<dim3(8, 16, 4), dim3(256), 0, stream>>>(psh, pth, spart);
    sinkhorn_kernel<<<dim3(NBLK), dim3(512), 0, stream>>>(spart, cpart, outpart, outp, flags);
}